// Round 7
// baseline (197.539 us; speedup 1.0000x reference)
//
#include <hip/hip_runtime.h>
#include <hip/hip_bf16.h>
#include <math.h>

// Problem constants (reference: B=2, T=2048, D_MODEL=1024, N_HEAD=16, D_HEAD=64)
constexpr int Bb   = 2;
constexpr int T    = 2048;
constexpr int C    = 1024;
constexpr int H    = 16;
constexpr int M    = Bb * T;   // 4096 rows
constexpr int NQKV = 3 * C;    // 3072

typedef __attribute__((ext_vector_type(8))) short bf16x8;
typedef __attribute__((ext_vector_type(4))) float f32x4;
typedef __attribute__((ext_vector_type(16))) float f32x16;

__device__ inline short f2bf(float f) {
    __hip_bfloat16 h = __float2bfloat16(f);
    return *reinterpret_cast<short*>(&h);
}

#if __has_builtin(__builtin_amdgcn_exp2f)
#define EXP2(x) __builtin_amdgcn_exp2f(x)
#else
#define EXP2(x) exp2f(x)
#endif

#define GLOBAL_AS __attribute__((address_space(1)))
#define LDS_AS    __attribute__((address_space(3)))

__device__ __forceinline__ void gload_lds16(const short* g, short* s) {
    __builtin_amdgcn_global_load_lds((const GLOBAL_AS void*)g, (LDS_AS void*)s, 16, 0, 0);
}

// ---------------------------------------------------------------------------
// Fused prep: x->bf16 (blocks 0..4095), w_qkv transpose (4096..7167),
// w_proj transpose (7168..8191). Unchanged (R2-proven).
// ---------------------------------------------------------------------------
__global__ __launch_bounds__(256)
void prep_all(const float* __restrict__ x, short* __restrict__ xb,
              const float* __restrict__ w_qkv, short* __restrict__ wqkvt,
              const float* __restrict__ w_proj, short* __restrict__ wprojt)
{
    __shared__ float tile[32][33];
    const int blk = blockIdx.x;
    const int tid = threadIdx.x;

    if (blk < 4096) {                       // cvt x
        const int i = blk * 1024 + tid * 4;
        const float4 v = *(const float4*)(x + i);
        short4 s;
        s.x = f2bf(v.x); s.y = f2bf(v.y); s.z = f2bf(v.z); s.w = f2bf(v.w);
        *(short4*)(xb + i) = s;
        return;
    }

    const bool isqkv = (blk < 7168);
    const int bidx = isqkv ? (blk - 4096) : (blk - 7168);
    const int nblk = isqkv ? 96 : 32;       // N/32
    const int N    = isqkv ? NQKV : C;
    const float* W = isqkv ? w_qkv : w_proj;
    short* Wt      = isqkv ? wqkvt : wprojt;

    const int n0 = (bidx % nblk) * 32, k0 = (bidx / nblk) * 32;
    const int tx = tid & 31, ty = tid >> 5;   // 32 x 8
#pragma unroll
    for (int i = 0; i < 32; i += 8)
        tile[ty + i][tx] = W[(size_t)(k0 + ty + i) * N + n0 + tx];
    __syncthreads();
#pragma unroll
    for (int i = 0; i < 32; i += 8)
        Wt[(size_t)(n0 + ty + i) * C + k0 + tx] = f2bf(tile[tx][ty + i]);
}

// ---------------------------------------------------------------------------
// QKV GEMM: 128x128 tile, BK=32, 2-phase prefetch double-buffer + XCD swizzle.
// Unchanged from R1 (proven).
// ---------------------------------------------------------------------------
__global__ __launch_bounds__(256)
void gemm_mfma(const short* __restrict__ A, const short* __restrict__ Bt,
               const float* __restrict__ bias, short* __restrict__ outp,
               int Ndim, int Kdim)
{
    __shared__ __align__(16) short As[2 * 128 * 32];   // 16 KB (double-buffered)
    __shared__ __align__(16) short Bs[2 * 128 * 32];   // 16 KB

    const int tid = threadIdx.x;
    const int w   = tid >> 6;
    const int l   = tid & 63;
    const int lk  = l & 15;
    const int lq  = l >> 4;

    const int gx  = gridDim.x;
    const int nwg = gx * gridDim.y;          // 768, divisible by 8
    const int cpx = nwg >> 3;
    const int bid = blockIdx.y * gx + blockIdx.x;
    const int swz = (bid & 7) * cpx + (bid >> 3);
    const int m0  = (swz / gx) * 128;
    const int n0  = (swz % gx) * 128;

    const int mw  = (w >> 1) * 64, nw = (w & 1) * 64;

    const int srow = w * 16 + (l >> 2);
    const int scol = (l & 3) * 8;

    const short* agp0 = A  + (size_t)(m0 + srow)      * Kdim + scol;
    const short* agp1 = A  + (size_t)(m0 + 64 + srow) * Kdim + scol;
    const short* bgp0 = Bt + (size_t)(n0 + srow)      * Kdim + scol;
    const short* bgp1 = Bt + (size_t)(n0 + 64 + srow) * Kdim + scol;

    short* ad0 = &As[w * 512];
    short* ad1 = &As[2048 + w * 512];
    short* bd0 = &Bs[w * 512];
    short* bd1 = &Bs[2048 + w * 512];

    f32x4 acc[4][4];
#pragma unroll
    for (int i = 0; i < 4; ++i)
#pragma unroll
        for (int j = 0; j < 4; ++j) acc[i][j] = (f32x4){0.f, 0.f, 0.f, 0.f};

    gload_lds16(agp0, ad0);
    gload_lds16(agp1, ad1);
    gload_lds16(bgp0, bd0);
    gload_lds16(bgp1, bd1);
    __syncthreads();

    int cur = 0;
    for (int k0 = 0; k0 < Kdim; k0 += 32) {
        const int coff = cur ? 4096 : 0;

        bf16x8 af[4], bfr[4];
#pragma unroll
        for (int mt = 0; mt < 4; ++mt)
            af[mt] = *(const bf16x8*)&As[coff + (mw + mt * 16 + lk) * 32 + lq * 8];
#pragma unroll
        for (int nt = 0; nt < 4; ++nt)
            bfr[nt] = *(const bf16x8*)&Bs[coff + (nw + nt * 16 + lk) * 32 + lq * 8];

        if (k0 + 32 < Kdim) {
            const int noff = cur ? 0 : 4096;
            gload_lds16(agp0 + k0 + 32, ad0 + noff);
            gload_lds16(agp1 + k0 + 32, ad1 + noff);
            gload_lds16(bgp0 + k0 + 32, bd0 + noff);
            gload_lds16(bgp1 + k0 + 32, bd1 + noff);
        }

#pragma unroll
        for (int mt = 0; mt < 4; ++mt)
#pragma unroll
            for (int nt = 0; nt < 4; ++nt)
                acc[mt][nt] = __builtin_amdgcn_mfma_f32_16x16x32_bf16(bfr[nt], af[mt], acc[mt][nt], 0, 0, 0);

        __syncthreads();
        cur ^= 1;
    }

    float4 bv[4];
#pragma unroll
    for (int nt = 0; nt < 4; ++nt)
        bv[nt] = *(const float4*)(bias + n0 + nw + nt * 16 + lq * 4);
#pragma unroll
    for (int mt = 0; mt < 4; ++mt) {
        short* rowp = outp + (size_t)(m0 + mw + mt * 16 + lk) * Ndim + n0 + nw + lq * 4;
#pragma unroll
        for (int nt = 0; nt < 4; ++nt) {
            short4 pk;
            pk.x = f2bf(acc[mt][nt][0] + bv[nt].x);
            pk.y = f2bf(acc[mt][nt][1] + bv[nt].y);
            pk.z = f2bf(acc[mt][nt][2] + bv[nt].z);
            pk.w = f2bf(acc[mt][nt][3] + bv[nt].w);
            *(short4*)(rowp + nt * 16) = pk;
        }
    }
}

// ---------------------------------------------------------------------------
// Proj GEMM: 64x128 tile, BK=32, 2-phase prefetch + XCD swizzle. Unchanged.
// ---------------------------------------------------------------------------
__global__ __launch_bounds__(256)
void gemm_mfma_proj(const short* __restrict__ A, const short* __restrict__ Bt,
                    const float* __restrict__ bias, float* __restrict__ outp,
                    int Ndim, int Kdim)
{
    __shared__ __align__(16) short As[2 * 64 * 32];    //  8 KB
    __shared__ __align__(16) short Bs[2 * 128 * 32];   // 16 KB

    const int tid = threadIdx.x;
    const int w   = tid >> 6;
    const int l   = tid & 63;
    const int lk  = l & 15;
    const int lq  = l >> 4;

    const int gx  = gridDim.x;
    const int nwg = gx * gridDim.y;          // 512, divisible by 8
    const int cpx = nwg >> 3;
    const int bid = blockIdx.y * gx + blockIdx.x;
    const int swz = (bid & 7) * cpx + (bid >> 3);
    const int m0  = (swz / gx) * 64;
    const int n0  = (swz % gx) * 128;

    const int mw  = (w & 1) * 32, nw = (w >> 1) * 64;

    const int srow = w * 16 + (l >> 2);
    const int scol = (l & 3) * 8;

    const short* agp  = A  + (size_t)(m0 + srow)      * Kdim + scol;
    const short* bgp0 = Bt + (size_t)(n0 + srow)      * Kdim + scol;
    const short* bgp1 = Bt + (size_t)(n0 + 64 + srow) * Kdim + scol;

    short* ad  = &As[w * 512];
    short* bd0 = &Bs[w * 512];
    short* bd1 = &Bs[2048 + w * 512];

    f32x4 acc[2][4];
#pragma unroll
    for (int i = 0; i < 2; ++i)
#pragma unroll
        for (int j = 0; j < 4; ++j) acc[i][j] = (f32x4){0.f, 0.f, 0.f, 0.f};

    gload_lds16(agp,  ad);
    gload_lds16(bgp0, bd0);
    gload_lds16(bgp1, bd1);
    __syncthreads();

    int cur = 0;
    for (int k0 = 0; k0 < Kdim; k0 += 32) {
        const int coffA = cur ? 2048 : 0;
        const int coffB = cur ? 4096 : 0;

        bf16x8 af[2], bfr[4];
#pragma unroll
        for (int mt = 0; mt < 2; ++mt)
            af[mt] = *(const bf16x8*)&As[coffA + (mw + mt * 16 + lk) * 32 + lq * 8];
#pragma unroll
        for (int nt = 0; nt < 4; ++nt)
            bfr[nt] = *(const bf16x8*)&Bs[coffB + (nw + nt * 16 + lk) * 32 + lq * 8];

        if (k0 + 32 < Kdim) {
            const int noffA = cur ? 0 : 2048;
            const int noffB = cur ? 0 : 4096;
            gload_lds16(agp  + k0 + 32, ad  + noffA);
            gload_lds16(bgp0 + k0 + 32, bd0 + noffB);
            gload_lds16(bgp1 + k0 + 32, bd1 + noffB);
        }

#pragma unroll
        for (int mt = 0; mt < 2; ++mt)
#pragma unroll
            for (int nt = 0; nt < 4; ++nt)
                acc[mt][nt] = __builtin_amdgcn_mfma_f32_16x16x32_bf16(bfr[nt], af[mt], acc[mt][nt], 0, 0, 0);

        __syncthreads();
        cur ^= 1;
    }

    float4 bv[4];
#pragma unroll
    for (int nt = 0; nt < 4; ++nt)
        bv[nt] = *(const float4*)(bias + n0 + nw + nt * 16 + lq * 4);
#pragma unroll
    for (int mt = 0; mt < 2; ++mt) {
        float* rowp = outp + (size_t)(m0 + mw + mt * 16 + lk) * Ndim + n0 + nw + lq * 4;
#pragma unroll
        for (int nt = 0; nt < 4; ++nt) {
            float4 v;
            v.x = acc[mt][nt][0] + bv[nt].x;
            v.y = acc[mt][nt][1] + bv[nt].y;
            v.z = acc[mt][nt][2] + bv[nt].z;
            v.w = acc[mt][nt][3] + bv[nt].w;
            *(float4*)(rowp + nt * 16) = v;
        }
    }
}

// ---------------------------------------------------------------------------
// MFMA flash attention v14 = v11's 32x32 fragment engine (halves LDS-read
// traffic: 128 vs 256 ds_read_b128 per block-tile; -17% MFMA cycles)
//  + v13's proven work layout (same 512-block grid, XCD-pinned bh,
//    (s, 23-s) pairing -- NOT v11's half-split that caused the 10.5%-
//    occupancy scheduling tail)
//  + v13's static-max softmax (exp2(S*SC - M0) exact; no max tree, no corr,
//    no cross-lane ops in the loop; l deferred to epilogue)
//  + diagonal-tile skip: wave w needs only key-blocks kb <= w on the last
//    tile (wave-uniform guard, compile-time s4 indexing) -- skips ~44% of
//    diagonal QK MFMA + exp + pack + PV.
// All index math byte-identical to correctness-verified v11/v13.
// ---------------------------------------------------------------------------
constexpr float SC = 0.18033688f;   // 0.125 * log2(e)
constexpr float M0 = 16.0f;         // static softmax shift (exact)

__global__ __launch_bounds__(256, 2)
void attn_mfma(const short* __restrict__ qkv, short* __restrict__ att)
{
    __shared__ __align__(16) short Ks[2][128 * 64];   // 2x16 KB, granule^row&7
    __shared__ __align__(16) short Vt[2][64 * 128];   // 2x16 KB, slot-permuted

    const int idx = blockIdx.x;              // 0..511
    const int xcd = idx & 7;
    const int j   = idx >> 3;                // 0..63
    const int bh  = xcd * 4 + (j & 3);       // 4 bh per XCD (L2 pinning)
    const int s   = j >> 2;                  // 0..15
    const int qt  = (s < 8) ? s : (23 - s);  // pair (s,s+8): (qt+1)+(16-qt)=17
    const int b   = bh >> 4;
    const int h   = bh & 15;
    const int qbase = qt * 128;
    const int nkt   = qt + 1;

    const int tid = threadIdx.x;
    const int w   = tid >> 6;                // 0..3
    const int l   = tid & 63;
    const int c31 = l & 31;
    const int hi  = l >> 5;

    const short* base = qkv + (size_t)b * T * 3072 + h * 64;

    // Q fragments (B-operand): lane owns q-col q_abs
    const int q_abs = qbase + w * 32 + c31;
    const short* qp = base + (size_t)q_abs * 3072 + hi * 8;
    bf16x8 qf[4];
#pragma unroll
    for (int ds = 0; ds < 4; ++ds)
        qf[ds] = *(const bf16x8*)(qp + ds * 16);

    f32x16 acc_o[2];
#pragma unroll
    for (int dt = 0; dt < 2; ++dt)
#pragma unroll
        for (int r = 0; r < 16; ++r) acc_o[dt][r] = 0.f;
    float lacc = 0.f;

    // K staging: per-thread granule (l&7) of row (l>>3), source col XOR'd
    const int kswz = 8 * ((l & 7) ^ (l >> 3));
    const int sw   = c31 & 7;                // QK read swizzle

    // V staging: thread owns keys {2l, 2l+1}, dims w*16 .. +15
    const int k0v = 2 * l;
    const int kk5 = k0v & 31;
    const int pos = (k0v >> 5) * 32 + ((kk5 >> 4) & 1) * 16 + ((kk5 >> 2) & 1) * 8
                  + ((kk5 >> 3) & 1) * 4 + (kk5 & 3);   // even
    const int vg  = pos >> 3;
    const int vpo = pos & 7;
    const int seg = w * 16;
    const int dmask = c31 & 15;              // Vt read swizzle source

    union { uint4 q[2]; unsigned int u[8]; } KA, KB;

    // ---- prologue: stage tile 0 into buffer 0 ----
#pragma unroll
    for (int rr = 0; rr < 4; ++rr) {
        const int rowbase = rr * 32 + w * 8;
        gload_lds16(base + 1024 + (size_t)(rowbase + (l >> 3)) * 3072 + kswz,
                    &Ks[0][rowbase * 64]);
    }
    {
        const short* vp = base + 2048 + (size_t)k0v * 3072 + seg;
        KA.q[0] = *(const uint4*)vp;
        KA.q[1] = *(const uint4*)(vp + 8);
        KB.q[0] = *(const uint4*)(vp + 3072);
        KB.q[1] = *(const uint4*)(vp + 3080);
#pragma unroll
        for (int dd = 0; dd < 16; ++dd) {
            const unsigned int w0 = KA.u[dd >> 1];
            const unsigned int w1 = KB.u[dd >> 1];
            const unsigned int pk = (dd & 1) ? ((w0 >> 16) | (w1 & 0xffff0000u))
                                             : ((w0 & 0xffffu) | (w1 << 16));
            *(unsigned int*)&Vt[0][(seg + dd) * 128 + ((vg ^ dd) << 3) + vpo] = pk;
        }
    }
    __syncthreads();

#pragma unroll 1
    for (int it = 0; it < nkt; ++it) {
        const int j0  = it * 128;
        const int buf = it & 1;
        const int nb  = buf ^ 1;
        const bool diag  = (it == nkt - 1);
        const int  ktmax = diag ? w : 3;     // wave-uniform kb bound

        // --- issue next-tile prefetch before compute (latency hides) ---
        if (it + 1 < nkt) {
            const int j1 = j0 + 128;
#pragma unroll
            for (int rr = 0; rr < 4; ++rr) {
                const int rowbase = rr * 32 + w * 8;
                gload_lds16(base + 1024 + (size_t)(j1 + rowbase + (l >> 3)) * 3072 + kswz,
                            &Ks[nb][rowbase * 64]);
            }
            const short* vp = base + 2048 + (size_t)(j1 + k0v) * 3072 + seg;
            KA.q[0] = *(const uint4*)vp;
            KA.q[1] = *(const uint4*)(vp + 8);
            KB.q[0] = *(const uint4*)(vp + 3072);
            KB.q[1] = *(const uint4*)(vp + 3080);
        }

        // --- S^T = K Q^T: s4[kb] covers keys kb*32.., col = q ---
        f32x16 s4[4];
        __builtin_amdgcn_s_setprio(1);
#pragma unroll
        for (int kb = 0; kb < 4; ++kb) {
            if (kb <= ktmax) {
                const short* krp = &Ks[buf][(kb * 32 + c31) * 64];
                f32x16 a;
#pragma unroll
                for (int r = 0; r < 16; ++r) a[r] = 0.f;
#pragma unroll
                for (int ds = 0; ds < 4; ++ds) {
                    const bf16x8 kf = *(const bf16x8*)&krp[((ds * 2 + hi) ^ sw) << 3];
                    a = __builtin_amdgcn_mfma_f32_32x32x16_bf16(kf, qf[ds], a, 0, 0, 0);
                }
                s4[kb] = a;
            }
        }
        __builtin_amdgcn_s_setprio(0);

        // --- causal mask: only the kb == w sub-block of the diagonal tile ---
        if (diag) {
#pragma unroll
            for (int kb = 0; kb < 4; ++kb) {
                if (kb == ktmax) {           // compile-time s4 index (rule #20)
#pragma unroll
                    for (int r = 0; r < 16; ++r) {
                        const int crow = (r & 3) + 8 * (r >> 2) + 4 * hi;
                        if (crow > c31) s4[kb][r] = -1e30f;
                    }
                }
            }
        }

        // --- static-max softmax: P = exp2(S*SC - M0); no cross-lane ops ---
#pragma unroll
        for (int kb = 0; kb < 4; ++kb) {
            if (kb <= ktmax) {
#pragma unroll
                for (int r = 0; r < 16; ++r)
                    s4[kb][r] = EXP2(fmaf(s4[kb][r], SC, -M0));
            }
        }

        float ps = 0.f;
#pragma unroll
        for (int kb = 0; kb < 4; ++kb) {
            if (kb <= ktmax) {
                float a0 = (s4[kb][0] + s4[kb][1]) + (s4[kb][2] + s4[kb][3]);
                float a1 = (s4[kb][4] + s4[kb][5]) + (s4[kb][6] + s4[kb][7]);
                float a2 = (s4[kb][8] + s4[kb][9]) + (s4[kb][10] + s4[kb][11]);
                float a3 = (s4[kb][12] + s4[kb][13]) + (s4[kb][14] + s4[kb][15]);
                ps += (a0 + a1) + (a2 + a3);
            }
        }
        lacc += ps;

        // --- O^T += V^T P^T: pf straight from regs; vf one b128 read ---
        __builtin_amdgcn_s_setprio(1);
#pragma unroll
        for (int kb = 0; kb < 4; ++kb) {
            if (kb <= ktmax) {
#pragma unroll
                for (int hh = 0; hh < 2; ++hh) {
                    union { unsigned int u[4]; bf16x8 v; } up;
#pragma unroll
                    for (int p = 0; p < 4; ++p)
                        up.u[p] = (unsigned int)(unsigned short)f2bf(s4[kb][hh * 8 + 2 * p])
                                | ((unsigned int)(unsigned short)f2bf(s4[kb][hh * 8 + 2 * p + 1]) << 16);
                    const int g = kb * 4 + hh * 2 + hi;
#pragma unroll
                    for (int dt = 0; dt < 2; ++dt) {
                        const bf16x8 vf = *(const bf16x8*)
                            &Vt[buf][(dt * 32 + c31) * 128 + ((g ^ dmask) << 3)];
                        acc_o[dt] = __builtin_amdgcn_mfma_f32_32x32x16_bf16(vf, up.v, acc_o[dt], 0, 0, 0);
                    }
                }
            }
        }
        __builtin_amdgcn_s_setprio(0);

        // --- write prefetched V into spare buffer (after its readers) ---
        if (it + 1 < nkt) {
#pragma unroll
            for (int dd = 0; dd < 16; ++dd) {
                const unsigned int w0 = KA.u[dd >> 1];
                const unsigned int w1 = KB.u[dd >> 1];
                const unsigned int pk = (dd & 1) ? ((w0 >> 16) | (w1 & 0xffff0000u))
                                                 : ((w0 & 0xffffu) | (w1 << 16));
                *(unsigned int*)&Vt[nb][(seg + dd) * 128 + ((vg ^ dd) << 3) + vpo] = pk;
            }
        }

        __syncthreads();   // drains K gloads + V writes, frees old buffers
    }

    // --- epilogue: O[q][d] = O^T[d][q]/l (l reduced across hi halves) ---
    const float ls  = lacc + __shfl_xor(lacc, 32);
    const float inv = 1.f / ls;
    short* op = att + ((size_t)(b * T + q_abs)) * 1024 + h * 64;
#pragma unroll
    for (int dt = 0; dt < 2; ++dt)
#pragma unroll
        for (int rg = 0; rg < 4; ++rg) {
            const int d0 = dt * 32 + 8 * rg + 4 * hi;
            short4 pk;
            pk.x = f2bf(acc_o[dt][rg * 4 + 0] * inv);
            pk.y = f2bf(acc_o[dt][rg * 4 + 1] * inv);
            pk.z = f2bf(acc_o[dt][rg * 4 + 2] * inv);
            pk.w = f2bf(acc_o[dt][rg * 4 + 3] * inv);
            *(short4*)(op + d0) = pk;
        }
}

// ---------------------------------------------------------------------------
extern "C" void kernel_launch(void* const* d_in, const int* in_sizes, int n_in,
                              void* d_out, int out_size, void* d_ws, size_t ws_size,
                              hipStream_t stream)
{
    const float* x      = (const float*)d_in[0];   // [B,T,C]
    const float* w_qkv  = (const float*)d_in[1];   // [C,3C]
    const float* b_qkv  = (const float*)d_in[2];   // [3C]
    const float* w_proj = (const float*)d_in[3];   // [C,C]
    const float* b_proj = (const float*)d_in[4];   // [C]
    float* out = (float*)d_out;                    // [B,T,C] fp32

    short* xb     = (short*)d_ws;                        //  8 MB
    short* wqkvt  = xb     + (size_t)M * C;              //  6 MB  [3072][1024]
    short* wprojt = wqkvt  + (size_t)NQKV * C;           //  2 MB  [1024][1024]
    short* qkvb   = wprojt + (size_t)C * C;              // 24 MB  [4096][3072]
    short* attb   = qkvb   + (size_t)M * NQKV;           //  8 MB  [4096][1024]

    prep_all<<<8192, 256, 0, stream>>>(x, xb, w_qkv, wqkvt, w_proj, wprojt);
    gemm_mfma<<<dim3(NQKV / 128, M / 128), 256, 0, stream>>>(xb, wqkvt, b_qkv, qkvb, NQKV, C);
    attn_mfma<<<512, 256, 0, stream>>>(qkvb, attb);
    gemm_mfma_proj<<<dim3(C / 128, M / 64), 256, 0, stream>>>(attb, wprojt, b_proj, out, C, C);
}

// Round 8
// 177.329 us; speedup vs baseline: 1.1140x; 1.1140x over previous
//
#include <hip/hip_runtime.h>
#include <hip/hip_bf16.h>
#include <math.h>

// Problem constants (reference: B=2, T=2048, D_MODEL=1024, N_HEAD=16, D_HEAD=64)
constexpr int Bb   = 2;
constexpr int T    = 2048;
constexpr int C    = 1024;
constexpr int H    = 16;
constexpr int M    = Bb * T;   // 4096 rows
constexpr int NQKV = 3 * C;    // 3072

typedef __attribute__((ext_vector_type(8))) short bf16x8;
typedef __attribute__((ext_vector_type(4))) float f32x4;

__device__ inline short f2bf(float f) {
    __hip_bfloat16 h = __float2bfloat16(f);
    return *reinterpret_cast<short*>(&h);
}

// HW packed f32x2 -> bf16x2 (RNE). No builtin on gfx950 (T12): inline asm.
__device__ __forceinline__ unsigned int cvt_pk_bf16(float lo, float hi) {
    unsigned int d;
    asm("v_cvt_pk_bf16_f32 %0, %1, %2" : "=v"(d) : "v"(lo), "v"(hi));
    return d;
}

#if __has_builtin(__builtin_amdgcn_exp2f)
#define EXP2(x) __builtin_amdgcn_exp2f(x)
#else
#define EXP2(x) exp2f(x)
#endif

#define GLOBAL_AS __attribute__((address_space(1)))
#define LDS_AS    __attribute__((address_space(3)))

__device__ __forceinline__ void gload_lds16(const short* g, short* s) {
    __builtin_amdgcn_global_load_lds((const GLOBAL_AS void*)g, (LDS_AS void*)s, 16, 0, 0);
}

// ---------------------------------------------------------------------------
// Fused prep: x->bf16 (blocks 0..4095), w_qkv transpose (4096..7167),
// w_proj transpose (7168..8191). Unchanged (R2-proven).
// ---------------------------------------------------------------------------
__global__ __launch_bounds__(256)
void prep_all(const float* __restrict__ x, short* __restrict__ xb,
              const float* __restrict__ w_qkv, short* __restrict__ wqkvt,
              const float* __restrict__ w_proj, short* __restrict__ wprojt)
{
    __shared__ float tile[32][33];
    const int blk = blockIdx.x;
    const int tid = threadIdx.x;

    if (blk < 4096) {                       // cvt x
        const int i = blk * 1024 + tid * 4;
        const float4 v = *(const float4*)(x + i);
        short4 s;
        s.x = f2bf(v.x); s.y = f2bf(v.y); s.z = f2bf(v.z); s.w = f2bf(v.w);
        *(short4*)(xb + i) = s;
        return;
    }

    const bool isqkv = (blk < 7168);
    const int bidx = isqkv ? (blk - 4096) : (blk - 7168);
    const int nblk = isqkv ? 96 : 32;       // N/32
    const int N    = isqkv ? NQKV : C;
    const float* W = isqkv ? w_qkv : w_proj;
    short* Wt      = isqkv ? wqkvt : wprojt;

    const int n0 = (bidx % nblk) * 32, k0 = (bidx / nblk) * 32;
    const int tx = tid & 31, ty = tid >> 5;   // 32 x 8
#pragma unroll
    for (int i = 0; i < 32; i += 8)
        tile[ty + i][tx] = W[(size_t)(k0 + ty + i) * N + n0 + tx];
    __syncthreads();
#pragma unroll
    for (int i = 0; i < 32; i += 8)
        Wt[(size_t)(n0 + ty + i) * C + k0 + tx] = f2bf(tile[tx][ty + i]);
}

// ---------------------------------------------------------------------------
// QKV GEMM: 128x128 tile, BK=32, 2-phase prefetch double-buffer + XCD swizzle.
// Unchanged from R1 (proven).
// ---------------------------------------------------------------------------
__global__ __launch_bounds__(256)
void gemm_mfma(const short* __restrict__ A, const short* __restrict__ Bt,
               const float* __restrict__ bias, short* __restrict__ outp,
               int Ndim, int Kdim)
{
    __shared__ __align__(16) short As[2 * 128 * 32];   // 16 KB (double-buffered)
    __shared__ __align__(16) short Bs[2 * 128 * 32];   // 16 KB

    const int tid = threadIdx.x;
    const int w   = tid >> 6;
    const int l   = tid & 63;
    const int lk  = l & 15;
    const int lq  = l >> 4;

    const int gx  = gridDim.x;
    const int nwg = gx * gridDim.y;          // 768, divisible by 8
    const int cpx = nwg >> 3;
    const int bid = blockIdx.y * gx + blockIdx.x;
    const int swz = (bid & 7) * cpx + (bid >> 3);
    const int m0  = (swz / gx) * 128;
    const int n0  = (swz % gx) * 128;

    const int mw  = (w >> 1) * 64, nw = (w & 1) * 64;

    const int srow = w * 16 + (l >> 2);
    const int scol = (l & 3) * 8;

    const short* agp0 = A  + (size_t)(m0 + srow)      * Kdim + scol;
    const short* agp1 = A  + (size_t)(m0 + 64 + srow) * Kdim + scol;
    const short* bgp0 = Bt + (size_t)(n0 + srow)      * Kdim + scol;
    const short* bgp1 = Bt + (size_t)(n0 + 64 + srow) * Kdim + scol;

    short* ad0 = &As[w * 512];
    short* ad1 = &As[2048 + w * 512];
    short* bd0 = &Bs[w * 512];
    short* bd1 = &Bs[2048 + w * 512];

    f32x4 acc[4][4];
#pragma unroll
    for (int i = 0; i < 4; ++i)
#pragma unroll
        for (int j = 0; j < 4; ++j) acc[i][j] = (f32x4){0.f, 0.f, 0.f, 0.f};

    gload_lds16(agp0, ad0);
    gload_lds16(agp1, ad1);
    gload_lds16(bgp0, bd0);
    gload_lds16(bgp1, bd1);
    __syncthreads();

    int cur = 0;
    for (int k0 = 0; k0 < Kdim; k0 += 32) {
        const int coff = cur ? 4096 : 0;

        bf16x8 af[4], bfr[4];
#pragma unroll
        for (int mt = 0; mt < 4; ++mt)
            af[mt] = *(const bf16x8*)&As[coff + (mw + mt * 16 + lk) * 32 + lq * 8];
#pragma unroll
        for (int nt = 0; nt < 4; ++nt)
            bfr[nt] = *(const bf16x8*)&Bs[coff + (nw + nt * 16 + lk) * 32 + lq * 8];

        if (k0 + 32 < Kdim) {
            const int noff = cur ? 0 : 4096;
            gload_lds16(agp0 + k0 + 32, ad0 + noff);
            gload_lds16(agp1 + k0 + 32, ad1 + noff);
            gload_lds16(bgp0 + k0 + 32, bd0 + noff);
            gload_lds16(bgp1 + k0 + 32, bd1 + noff);
        }

#pragma unroll
        for (int mt = 0; mt < 4; ++mt)
#pragma unroll
            for (int nt = 0; nt < 4; ++nt)
                acc[mt][nt] = __builtin_amdgcn_mfma_f32_16x16x32_bf16(bfr[nt], af[mt], acc[mt][nt], 0, 0, 0);

        __syncthreads();
        cur ^= 1;
    }

    float4 bv[4];
#pragma unroll
    for (int nt = 0; nt < 4; ++nt)
        bv[nt] = *(const float4*)(bias + n0 + nw + nt * 16 + lq * 4);
#pragma unroll
    for (int mt = 0; mt < 4; ++mt) {
        short* rowp = outp + (size_t)(m0 + mw + mt * 16 + lk) * Ndim + n0 + nw + lq * 4;
#pragma unroll
        for (int nt = 0; nt < 4; ++nt) {
            short4 pk;
            pk.x = f2bf(acc[mt][nt][0] + bv[nt].x);
            pk.y = f2bf(acc[mt][nt][1] + bv[nt].y);
            pk.z = f2bf(acc[mt][nt][2] + bv[nt].z);
            pk.w = f2bf(acc[mt][nt][3] + bv[nt].w);
            *(short4*)(rowp + nt * 16) = pk;
        }
    }
}

// ---------------------------------------------------------------------------
// Proj GEMM: 64x128 tile, BK=32, 2-phase prefetch + XCD swizzle. Unchanged.
// ---------------------------------------------------------------------------
__global__ __launch_bounds__(256)
void gemm_mfma_proj(const short* __restrict__ A, const short* __restrict__ Bt,
                    const float* __restrict__ bias, float* __restrict__ outp,
                    int Ndim, int Kdim)
{
    __shared__ __align__(16) short As[2 * 64 * 32];    //  8 KB
    __shared__ __align__(16) short Bs[2 * 128 * 32];   // 16 KB

    const int tid = threadIdx.x;
    const int w   = tid >> 6;
    const int l   = tid & 63;
    const int lk  = l & 15;
    const int lq  = l >> 4;

    const int gx  = gridDim.x;
    const int nwg = gx * gridDim.y;          // 512, divisible by 8
    const int cpx = nwg >> 3;
    const int bid = blockIdx.y * gx + blockIdx.x;
    const int swz = (bid & 7) * cpx + (bid >> 3);
    const int m0  = (swz / gx) * 64;
    const int n0  = (swz % gx) * 128;

    const int mw  = (w & 1) * 32, nw = (w >> 1) * 64;

    const int srow = w * 16 + (l >> 2);
    const int scol = (l & 3) * 8;

    const short* agp  = A  + (size_t)(m0 + srow)      * Kdim + scol;
    const short* bgp0 = Bt + (size_t)(n0 + srow)      * Kdim + scol;
    const short* bgp1 = Bt + (size_t)(n0 + 64 + srow) * Kdim + scol;

    short* ad  = &As[w * 512];
    short* bd0 = &Bs[w * 512];
    short* bd1 = &Bs[2048 + w * 512];

    f32x4 acc[2][4];
#pragma unroll
    for (int i = 0; i < 2; ++i)
#pragma unroll
        for (int j = 0; j < 4; ++j) acc[i][j] = (f32x4){0.f, 0.f, 0.f, 0.f};

    gload_lds16(agp,  ad);
    gload_lds16(bgp0, bd0);
    gload_lds16(bgp1, bd1);
    __syncthreads();

    int cur = 0;
    for (int k0 = 0; k0 < Kdim; k0 += 32) {
        const int coffA = cur ? 2048 : 0;
        const int coffB = cur ? 4096 : 0;

        bf16x8 af[2], bfr[4];
#pragma unroll
        for (int mt = 0; mt < 2; ++mt)
            af[mt] = *(const bf16x8*)&As[coffA + (mw + mt * 16 + lk) * 32 + lq * 8];
#pragma unroll
        for (int nt = 0; nt < 4; ++nt)
            bfr[nt] = *(const bf16x8*)&Bs[coffB + (nw + nt * 16 + lk) * 32 + lq * 8];

        if (k0 + 32 < Kdim) {
            const int noffA = cur ? 0 : 2048;
            const int noffB = cur ? 0 : 4096;
            gload_lds16(agp  + k0 + 32, ad  + noffA);
            gload_lds16(bgp0 + k0 + 32, bd0 + noffB);
            gload_lds16(bgp1 + k0 + 32, bd1 + noffB);
        }

#pragma unroll
        for (int mt = 0; mt < 2; ++mt)
#pragma unroll
            for (int nt = 0; nt < 4; ++nt)
                acc[mt][nt] = __builtin_amdgcn_mfma_f32_16x16x32_bf16(bfr[nt], af[mt], acc[mt][nt], 0, 0, 0);

        __syncthreads();
        cur ^= 1;
    }

    float4 bv[4];
#pragma unroll
    for (int nt = 0; nt < 4; ++nt)
        bv[nt] = *(const float4*)(bias + n0 + nw + nt * 16 + lq * 4);
#pragma unroll
    for (int mt = 0; mt < 2; ++mt) {
        float* rowp = outp + (size_t)(m0 + mw + mt * 16 + lk) * Ndim + n0 + nw + lq * 4;
#pragma unroll
        for (int nt = 0; nt < 4; ++nt) {
            float4 v;
            v.x = acc[mt][nt][0] + bv[nt].x;
            v.y = acc[mt][nt][1] + bv[nt].y;
            v.z = acc[mt][nt][2] + bv[nt].z;
            v.w = acc[mt][nt][3] + bv[nt].w;
            *(float4*)(rowp + nt * 16) = v;
        }
    }
}

// ---------------------------------------------------------------------------
// MFMA flash attention v15 = v13 (best: 41.4us) + two VALU trims:
//  (a) P-pack via HW v_cvt_pk_bf16_f32 (1 op per dword) instead of
//      2x __float2bfloat16 sw-sequences + or (~5 ops each): ~350 -> 32
//      VALU ops/wave/tile on the pack path.
//  (b) diagonal-tile kt-skip: on the last tile wave w (q-rows w*16..+15)
//      needs only key-blocks kt <= w; kt > w is fully causal-masked (P=0,
//      fed as literal zero where a PV chunk straddles). Wave-uniform guard,
//      compile-time s4 indexing. ~44% of diagonal-tile work skipped.
// Structure (128-row q-tiles, 8 waves, K+V dbuf, 1 barrier/tile, static-max
// softmax, XCD-pinned (s,s+8) pairing) byte-identical to v13.
// ---------------------------------------------------------------------------
constexpr int LDV = 136;            // Vt padded leading dim
constexpr float SC = 0.18033688f;   // 0.125 * log2(e)
constexpr float M0 = 16.0f;         // static softmax shift (exact)

__global__ __launch_bounds__(512, 2)
void attn_mfma(const short* __restrict__ qkv, short* __restrict__ att)
{
    __shared__ __align__(16) short Ks[2][128 * 64];   // swizzled [key][d] 2x16 KB
    __shared__ __align__(16) short Vt[2][64 * LDV];   // permuted [d][key] 2x17 KB

    const int idx = blockIdx.x;
    const int xcd = idx & 7;
    const int j   = idx >> 3;                // 0..63
    const int bh  = xcd * 4 + (j & 3);
    const int s   = j >> 2;                  // 0..15
    const int qt  = (s < 8) ? s : (23 - s);  // pair (s,s+8): (qt+1)+(16-qt)=17
    const int b   = bh >> 4;
    const int h   = bh & 15;
    const int qbase = qt * 128;

    const int tid = threadIdx.x;
    const int w   = tid >> 6;                // 0..7
    const int l   = tid & 63;
    const int lk  = l & 15;
    const int lq  = l >> 4;

    const short* base = qkv + (size_t)b * T * 3072 + h * 64;

    // Q fragments (B-operand of S^T); lane owns q-row q_abs
    const int q_abs = qbase + w * 16 + lk;
    const short* qp = base + (size_t)q_abs * 3072 + lq * 8;
    const bf16x8 qf0 = *(const bf16x8*)qp;
    const bf16x8 qf1 = *(const bf16x8*)(qp + 32);

    f32x4 acc_o[4];
#pragma unroll
    for (int dt = 0; dt < 4; ++dt) acc_o[dt] = (f32x4){0.f, 0.f, 0.f, 0.f};
    float lacc = 0.f;                        // deferred per-lane l partial

    const int krow   = l >> 3;
    const int kcolsw = 8 * ((l & 7) ^ (l >> 3));
    const int swz    = lk & 7;

    const int kg   = tid & 31;
    const int vd0  = ((tid >> 5) & 7) * 8;
    const int pcol = ((kg & 24) | ((kg & 3) << 1) | ((kg >> 2) & 1)) * 4;

    const int nkt = qt + 1;

    bf16x8 vv[4];

    // --- prologue: stage tile 0 (full latency paid once) ---
    if (w < 4) {
#pragma unroll
        for (int rr = 0; rr < 4; ++rr) {
            const int g = w * 32 + rr * 8;
            gload_lds16(base + 1024 + (size_t)(g + krow) * 3072 + kcolsw, &Ks[0][g * 64]);
        }
    } else {
        const short* vp = base + 2048 + (size_t)(kg * 4) * 3072 + vd0;
#pragma unroll
        for (int kk = 0; kk < 4; ++kk)
            vv[kk] = *(const bf16x8*)(vp + (size_t)kk * 3072);
#pragma unroll
        for (int d = 0; d < 8; ++d) {
            short4 pk;
            pk.x = vv[0][d]; pk.y = vv[1][d]; pk.z = vv[2][d]; pk.w = vv[3][d];
            *(short4*)&Vt[0][(vd0 + d) * LDV + pcol] = pk;
        }
    }
    __syncthreads();

#pragma unroll 1
    for (int it = 0; it < nkt; ++it) {
        const int j0  = it * 128;
        const int buf = it & 1;
        const int nb  = buf ^ 1;
        const bool diag  = (it == nkt - 1);
        const int  ktmax = diag ? w : 7;     // wave-uniform kt bound

        // --- issue next-tile prefetch before compute (latency hides) ---
        if (it + 1 < nkt) {
            const int j1 = j0 + 128;
            if (w < 4) {
#pragma unroll
                for (int rr = 0; rr < 4; ++rr) {
                    const int g = w * 32 + rr * 8;
                    gload_lds16(base + 1024 + (size_t)(j1 + g + krow) * 3072 + kcolsw,
                                &Ks[nb][g * 64]);
                }
            } else {
                const short* vp = base + 2048 + (size_t)(j1 + kg * 4) * 3072 + vd0;
#pragma unroll
                for (int kk = 0; kk < 4; ++kk)
                    vv[kk] = *(const bf16x8*)(vp + (size_t)kk * 3072);
            }
        }

        // --- S^T = K Q^T: s4[kt][r] = S[key = j0 + kt*16 + lq*4 + r][q = lk] ---
        f32x4 s4[8];
        __builtin_amdgcn_s_setprio(1);
#pragma unroll
        for (int kt = 0; kt < 8; ++kt) {
            if (kt <= ktmax) {
                const int row = kt * 16 + lk;
                const bf16x8 kf0 = *(const bf16x8*)&Ks[buf][row * 64 + 8 * (lq ^ swz)];
                const bf16x8 kf1 = *(const bf16x8*)&Ks[buf][row * 64 + 8 * ((lq + 4) ^ swz)];
                f32x4 a = (f32x4){0.f, 0.f, 0.f, 0.f};
                a = __builtin_amdgcn_mfma_f32_16x16x32_bf16(kf0, qf0, a, 0, 0, 0);
                a = __builtin_amdgcn_mfma_f32_16x16x32_bf16(kf1, qf1, a, 0, 0, 0);
                s4[kt] = a;
            }
        }
        __builtin_amdgcn_s_setprio(0);

        // --- causal mask: only the kt == w sub-block of the diagonal tile ---
        if (diag) {
#pragma unroll
            for (int kt = 0; kt < 8; ++kt) {
                if (kt == ktmax) {           // compile-time s4 index (rule #20)
#pragma unroll
                    for (int r = 0; r < 4; ++r)
                        if (j0 + kt * 16 + lq * 4 + r > q_abs) s4[kt][r] = -1e30f;
                }
            }
        }

        // --- static-max softmax: P = exp2(S*SC - M0); no cross-lane ops ---
#pragma unroll
        for (int kt = 0; kt < 8; ++kt) {
            if (kt <= ktmax) {
#pragma unroll
                for (int r = 0; r < 4; ++r)
                    s4[kt][r] = EXP2(fmaf(s4[kt][r], SC, -M0));
            }
        }

        float ps = 0.f;
#pragma unroll
        for (int kt = 0; kt < 8; ++kt)
            if (kt <= ktmax)
                ps += (s4[kt][0] + s4[kt][1]) + (s4[kt][2] + s4[kt][3]);
        lacc += ps;

        // --- pack P rows to dwords: HW cvt_pk (1 op each) ---
        unsigned int d0[8], d1[8];
#pragma unroll
        for (int kt = 0; kt < 8; ++kt) {
            if (kt <= ktmax) {
                d0[kt] = cvt_pk_bf16(s4[kt][0], s4[kt][1]);
                d1[kt] = cvt_pk_bf16(s4[kt][2], s4[kt][3]);
            } else {
                d0[kt] = 0u; d1[kt] = 0u;    // fully-masked block: P = 0
            }
        }

        // --- O^T += V^T P^T: pf straight from regs; vf one b128 read ---
        __builtin_amdgcn_s_setprio(1);
#pragma unroll
        for (int kc = 0; kc < 4; ++kc) {
            if (kc * 2 <= ktmax) {           // both kts masked -> skip chunk
                union { unsigned int u[4]; bf16x8 v; } up;
                up.u[0] = d0[kc * 2];
                up.u[1] = d1[kc * 2];
                up.u[2] = d0[kc * 2 + 1];
                up.u[3] = d1[kc * 2 + 1];
                const bf16x8 pf = up.v;
#pragma unroll
                for (int dt = 0; dt < 4; ++dt) {
                    const bf16x8 vf = *(const bf16x8*)&Vt[buf][(dt * 16 + lk) * LDV + kc * 32 + lq * 8];
                    acc_o[dt] = __builtin_amdgcn_mfma_f32_16x16x32_bf16(vf, pf, acc_o[dt], 0, 0, 0);
                }
            }
        }
        __builtin_amdgcn_s_setprio(0);

        // --- write prefetched V into the spare buffer (after its readers) ---
        if (it + 1 < nkt && w >= 4) {
#pragma unroll
            for (int d = 0; d < 8; ++d) {
                short4 pk;
                pk.x = vv[0][d]; pk.y = vv[1][d]; pk.z = vv[2][d]; pk.w = vv[3][d];
                *(short4*)&Vt[nb][(vd0 + d) * LDV + pcol] = pk;
            }
        }

        __syncthreads();   // single barrier: drains K gloads + V writes, frees old bufs
    }

    // --- epilogue: reduce l across the 4 lq-lanes, then O = O^T/l ---
    float ls = lacc;
    ls += __shfl_xor(ls, 16);
    ls += __shfl_xor(ls, 32);
    const float inv = 1.f / ls;
    short* op = att + ((size_t)(b * T + q_abs)) * 1024 + h * 64;
#pragma unroll
    for (int dt = 0; dt < 4; ++dt) {
        const unsigned int e0 = cvt_pk_bf16(acc_o[dt][0] * inv, acc_o[dt][1] * inv);
        const unsigned int e1 = cvt_pk_bf16(acc_o[dt][2] * inv, acc_o[dt][3] * inv);
        uint2 pk2; pk2.x = e0; pk2.y = e1;
        *(uint2*)(op + dt * 16 + lq * 4) = pk2;
    }
}

// ---------------------------------------------------------------------------
extern "C" void kernel_launch(void* const* d_in, const int* in_sizes, int n_in,
                              void* d_out, int out_size, void* d_ws, size_t ws_size,
                              hipStream_t stream)
{
    const float* x      = (const float*)d_in[0];   // [B,T,C]
    const float* w_qkv  = (const float*)d_in[1];   // [C,3C]
    const float* b_qkv  = (const float*)d_in[2];   // [3C]
    const float* w_proj = (const float*)d_in[3];   // [C,C]
    const float* b_proj = (const float*)d_in[4];   // [C]
    float* out = (float*)d_out;                    // [B,T,C] fp32

    short* xb     = (short*)d_ws;                        //  8 MB
    short* wqkvt  = xb     + (size_t)M * C;              //  6 MB  [3072][1024]
    short* wprojt = wqkvt  + (size_t)NQKV * C;           //  2 MB  [1024][1024]
    short* qkvb   = wprojt + (size_t)C * C;              // 24 MB  [4096][3072]
    short* attb   = qkvb   + (size_t)M * NQKV;           //  8 MB  [4096][1024]

    prep_all<<<8192, 256, 0, stream>>>(x, xb, w_qkv, wqkvt, w_proj, wprojt);
    gemm_mfma<<<dim3(NQKV / 128, M / 128), 256, 0, stream>>>(xb, wqkvt, b_qkv, qkvb, NQKV, C);
    attn_mfma<<<512, 512, 0, stream>>>(qkvb, attb);
    gemm_mfma_proj<<<dim3(C / 128, M / 64), 256, 0, stream>>>(attb, wprojt, b_proj, out, C, C);
}

// Round 9
// 174.675 us; speedup vs baseline: 1.1309x; 1.0152x over previous
//
#include <hip/hip_runtime.h>
#include <hip/hip_bf16.h>
#include <math.h>

// Problem constants (reference: B=2, T=2048, D_MODEL=1024, N_HEAD=16, D_HEAD=64)
constexpr int Bb   = 2;
constexpr int T    = 2048;
constexpr int C    = 1024;
constexpr int H    = 16;
constexpr int M    = Bb * T;   // 4096 rows
constexpr int NQKV = 3 * C;    // 3072

typedef __attribute__((ext_vector_type(8))) short bf16x8;
typedef __attribute__((ext_vector_type(4))) float f32x4;
typedef __attribute__((ext_vector_type(16))) float f32x16;

__device__ inline short f2bf(float f) {
    __hip_bfloat16 h = __float2bfloat16(f);
    return *reinterpret_cast<short*>(&h);
}

#if __has_builtin(__builtin_amdgcn_exp2f)
#define EXP2(x) __builtin_amdgcn_exp2f(x)
#else
#define EXP2(x) exp2f(x)
#endif

#define GLOBAL_AS __attribute__((address_space(1)))
#define LDS_AS    __attribute__((address_space(3)))

__device__ __forceinline__ void gload_lds16(const short* g, short* s) {
    __builtin_amdgcn_global_load_lds((const GLOBAL_AS void*)g, (LDS_AS void*)s, 16, 0, 0);
}

// ---------------------------------------------------------------------------
// Fused prep: x->bf16 (blocks 0..4095), w_qkv transpose (4096..7167),
// w_proj transpose (7168..8191). Unchanged (R2-proven).
// ---------------------------------------------------------------------------
__global__ __launch_bounds__(256)
void prep_all(const float* __restrict__ x, short* __restrict__ xb,
              const float* __restrict__ w_qkv, short* __restrict__ wqkvt,
              const float* __restrict__ w_proj, short* __restrict__ wprojt)
{
    __shared__ float tile[32][33];
    const int blk = blockIdx.x;
    const int tid = threadIdx.x;

    if (blk < 4096) {                       // cvt x
        const int i = blk * 1024 + tid * 4;
        const float4 v = *(const float4*)(x + i);
        short4 s;
        s.x = f2bf(v.x); s.y = f2bf(v.y); s.z = f2bf(v.z); s.w = f2bf(v.w);
        *(short4*)(xb + i) = s;
        return;
    }

    const bool isqkv = (blk < 7168);
    const int bidx = isqkv ? (blk - 4096) : (blk - 7168);
    const int nblk = isqkv ? 96 : 32;       // N/32
    const int N    = isqkv ? NQKV : C;
    const float* W = isqkv ? w_qkv : w_proj;
    short* Wt      = isqkv ? wqkvt : wprojt;

    const int n0 = (bidx % nblk) * 32, k0 = (bidx / nblk) * 32;
    const int tx = tid & 31, ty = tid >> 5;   // 32 x 8
#pragma unroll
    for (int i = 0; i < 32; i += 8)
        tile[ty + i][tx] = W[(size_t)(k0 + ty + i) * N + n0 + tx];
    __syncthreads();
#pragma unroll
    for (int i = 0; i < 32; i += 8)
        Wt[(size_t)(n0 + ty + i) * C + k0 + tx] = f2bf(tile[tx][ty + i]);
}

// ---------------------------------------------------------------------------
// QKV GEMM: 128x128 tile, BK=32, 2-phase prefetch double-buffer + XCD swizzle.
// Unchanged from R1 (proven).
// ---------------------------------------------------------------------------
__global__ __launch_bounds__(256)
void gemm_mfma(const short* __restrict__ A, const short* __restrict__ Bt,
               const float* __restrict__ bias, short* __restrict__ outp,
               int Ndim, int Kdim)
{
    __shared__ __align__(16) short As[2 * 128 * 32];   // 16 KB (double-buffered)
    __shared__ __align__(16) short Bs[2 * 128 * 32];   // 16 KB

    const int tid = threadIdx.x;
    const int w   = tid >> 6;
    const int l   = tid & 63;
    const int lk  = l & 15;
    const int lq  = l >> 4;

    const int gx  = gridDim.x;
    const int nwg = gx * gridDim.y;          // 768, divisible by 8
    const int cpx = nwg >> 3;
    const int bid = blockIdx.y * gx + blockIdx.x;
    const int swz = (bid & 7) * cpx + (bid >> 3);
    const int m0  = (swz / gx) * 128;
    const int n0  = (swz % gx) * 128;

    const int mw  = (w >> 1) * 64, nw = (w & 1) * 64;

    const int srow = w * 16 + (l >> 2);
    const int scol = (l & 3) * 8;

    const short* agp0 = A  + (size_t)(m0 + srow)      * Kdim + scol;
    const short* agp1 = A  + (size_t)(m0 + 64 + srow) * Kdim + scol;
    const short* bgp0 = Bt + (size_t)(n0 + srow)      * Kdim + scol;
    const short* bgp1 = Bt + (size_t)(n0 + 64 + srow) * Kdim + scol;

    short* ad0 = &As[w * 512];
    short* ad1 = &As[2048 + w * 512];
    short* bd0 = &Bs[w * 512];
    short* bd1 = &Bs[2048 + w * 512];

    f32x4 acc[4][4];
#pragma unroll
    for (int i = 0; i < 4; ++i)
#pragma unroll
        for (int j = 0; j < 4; ++j) acc[i][j] = (f32x4){0.f, 0.f, 0.f, 0.f};

    gload_lds16(agp0, ad0);
    gload_lds16(agp1, ad1);
    gload_lds16(bgp0, bd0);
    gload_lds16(bgp1, bd1);
    __syncthreads();

    int cur = 0;
    for (int k0 = 0; k0 < Kdim; k0 += 32) {
        const int coff = cur ? 4096 : 0;

        bf16x8 af[4], bfr[4];
#pragma unroll
        for (int mt = 0; mt < 4; ++mt)
            af[mt] = *(const bf16x8*)&As[coff + (mw + mt * 16 + lk) * 32 + lq * 8];
#pragma unroll
        for (int nt = 0; nt < 4; ++nt)
            bfr[nt] = *(const bf16x8*)&Bs[coff + (nw + nt * 16 + lk) * 32 + lq * 8];

        if (k0 + 32 < Kdim) {
            const int noff = cur ? 0 : 4096;
            gload_lds16(agp0 + k0 + 32, ad0 + noff);
            gload_lds16(agp1 + k0 + 32, ad1 + noff);
            gload_lds16(bgp0 + k0 + 32, bd0 + noff);
            gload_lds16(bgp1 + k0 + 32, bd1 + noff);
        }

#pragma unroll
        for (int mt = 0; mt < 4; ++mt)
#pragma unroll
            for (int nt = 0; nt < 4; ++nt)
                acc[mt][nt] = __builtin_amdgcn_mfma_f32_16x16x32_bf16(bfr[nt], af[mt], acc[mt][nt], 0, 0, 0);

        __syncthreads();
        cur ^= 1;
    }

    float4 bv[4];
#pragma unroll
    for (int nt = 0; nt < 4; ++nt)
        bv[nt] = *(const float4*)(bias + n0 + nw + nt * 16 + lq * 4);
#pragma unroll
    for (int mt = 0; mt < 4; ++mt) {
        short* rowp = outp + (size_t)(m0 + mw + mt * 16 + lk) * Ndim + n0 + nw + lq * 4;
#pragma unroll
        for (int nt = 0; nt < 4; ++nt) {
            short4 pk;
            pk.x = f2bf(acc[mt][nt][0] + bv[nt].x);
            pk.y = f2bf(acc[mt][nt][1] + bv[nt].y);
            pk.z = f2bf(acc[mt][nt][2] + bv[nt].z);
            pk.w = f2bf(acc[mt][nt][3] + bv[nt].w);
            *(short4*)(rowp + nt * 16) = pk;
        }
    }
}

// ---------------------------------------------------------------------------
// Proj GEMM: 64x128 tile, BK=32, 2-phase prefetch + XCD swizzle. Unchanged.
// ---------------------------------------------------------------------------
__global__ __launch_bounds__(256)
void gemm_mfma_proj(const short* __restrict__ A, const short* __restrict__ Bt,
                    const float* __restrict__ bias, float* __restrict__ outp,
                    int Ndim, int Kdim)
{
    __shared__ __align__(16) short As[2 * 64 * 32];    //  8 KB
    __shared__ __align__(16) short Bs[2 * 128 * 32];   // 16 KB

    const int tid = threadIdx.x;
    const int w   = tid >> 6;
    const int l   = tid & 63;
    const int lk  = l & 15;
    const int lq  = l >> 4;

    const int gx  = gridDim.x;
    const int nwg = gx * gridDim.y;          // 512, divisible by 8
    const int cpx = nwg >> 3;
    const int bid = blockIdx.y * gx + blockIdx.x;
    const int swz = (bid & 7) * cpx + (bid >> 3);
    const int m0  = (swz / gx) * 64;
    const int n0  = (swz % gx) * 128;

    const int mw  = (w & 1) * 32, nw = (w >> 1) * 64;

    const int srow = w * 16 + (l >> 2);
    const int scol = (l & 3) * 8;

    const short* agp  = A  + (size_t)(m0 + srow)      * Kdim + scol;
    const short* bgp0 = Bt + (size_t)(n0 + srow)      * Kdim + scol;
    const short* bgp1 = Bt + (size_t)(n0 + 64 + srow) * Kdim + scol;

    short* ad  = &As[w * 512];
    short* bd0 = &Bs[w * 512];
    short* bd1 = &Bs[2048 + w * 512];

    f32x4 acc[2][4];
#pragma unroll
    for (int i = 0; i < 2; ++i)
#pragma unroll
        for (int j = 0; j < 4; ++j) acc[i][j] = (f32x4){0.f, 0.f, 0.f, 0.f};

    gload_lds16(agp,  ad);
    gload_lds16(bgp0, bd0);
    gload_lds16(bgp1, bd1);
    __syncthreads();

    int cur = 0;
    for (int k0 = 0; k0 < Kdim; k0 += 32) {
        const int coffA = cur ? 2048 : 0;
        const int coffB = cur ? 4096 : 0;

        bf16x8 af[2], bfr[4];
#pragma unroll
        for (int mt = 0; mt < 2; ++mt)
            af[mt] = *(const bf16x8*)&As[coffA + (mw + mt * 16 + lk) * 32 + lq * 8];
#pragma unroll
        for (int nt = 0; nt < 4; ++nt)
            bfr[nt] = *(const bf16x8*)&Bs[coffB + (nw + nt * 16 + lk) * 32 + lq * 8];

        if (k0 + 32 < Kdim) {
            const int noffA = cur ? 0 : 2048;
            const int noffB = cur ? 0 : 4096;
            gload_lds16(agp  + k0 + 32, ad  + noffA);
            gload_lds16(bgp0 + k0 + 32, bd0 + noffB);
            gload_lds16(bgp1 + k0 + 32, bd1 + noffB);
        }

#pragma unroll
        for (int mt = 0; mt < 2; ++mt)
#pragma unroll
            for (int nt = 0; nt < 4; ++nt)
                acc[mt][nt] = __builtin_amdgcn_mfma_f32_16x16x32_bf16(bfr[nt], af[mt], acc[mt][nt], 0, 0, 0);

        __syncthreads();
        cur ^= 1;
    }

    float4 bv[4];
#pragma unroll
    for (int nt = 0; nt < 4; ++nt)
        bv[nt] = *(const float4*)(bias + n0 + nw + nt * 16 + lq * 4);
#pragma unroll
    for (int mt = 0; mt < 2; ++mt) {
        float* rowp = outp + (size_t)(m0 + mw + mt * 16 + lk) * Ndim + n0 + nw + lq * 4;
#pragma unroll
        for (int nt = 0; nt < 4; ++nt) {
            float4 v;
            v.x = acc[mt][nt][0] + bv[nt].x;
            v.y = acc[mt][nt][1] + bv[nt].y;
            v.z = acc[mt][nt][2] + bv[nt].z;
            v.w = acc[mt][nt][3] + bv[nt].w;
            *(float4*)(rowp + nt * 16) = v;
        }
    }
}

// ---------------------------------------------------------------------------
// MFMA flash attention v16 = v13's outer structure (best: 41.4us) with
// v11's 32x32x16 engine via a WAVE-PAIR KEY-SPLIT:
//  - 512 blocks x 8 waves, 128-row q-tiles, XCD-pinned (s, s+8) pairing,
//    K+V double-buffer, ONE barrier/tile, static-max softmax -- all v13.
//  - Wave (pair = w>>1, half = w&1): pair owns 32 q-rows; half owns keys
//    [64*half, 64*half+64) of each 128-key tile. Per wave: 8 QK + 8 PV
//    ds_read_b128 = HALF of v13's LDS-read traffic at the SAME 16 waves/CU
//    (the untested cell: v11/v14 halved LDS only at halved occupancy).
//  - Static-max softmax makes the two key-halves ADDITIVE: one LDS
//    exchange + add per q-tile at the epilogue (no online merge).
//  - All 32x32 index math (K swizzle, slot-permuted Vt, granule-XOR reads,
//    Q frags) verbatim from harness-passed v11. Plain f2bf pack (m240:
//    don't hand-write cvt_pk). No dynamic guards (v15 lesson).
// ---------------------------------------------------------------------------
constexpr float SC = 0.18033688f;   // 0.125 * log2(e)
constexpr float M0 = 16.0f;         // static softmax shift (exact)

__global__ __launch_bounds__(512, 2)
void attn_mfma(const short* __restrict__ qkv, short* __restrict__ att)
{
    __shared__ __align__(16) short Ks[2][128 * 64];   // 2x16 KB, granule^row&7
    __shared__ __align__(16) short Vt[2][64 * 128];   // 2x16 KB, slot-permuted

    const int idx = blockIdx.x;              // 0..511
    const int xcd = idx & 7;
    const int j   = idx >> 3;                // 0..63
    const int bh  = xcd * 4 + (j & 3);       // 4 bh per XCD (L2 pinning)
    const int s   = j >> 2;                  // 0..15
    const int qt  = (s < 8) ? s : (23 - s);  // pair (s,s+8): (qt+1)+(16-qt)=17
    const int b   = bh >> 4;
    const int h   = bh & 15;
    const int qbase = qt * 128;
    const int nkt   = qt + 1;

    const int tid = threadIdx.x;
    const int w    = tid >> 6;               // 0..7
    const int l    = tid & 63;
    const int c31  = l & 31;
    const int hi   = l >> 5;
    const int pair = w >> 1;                 // 0..3: owns 32 q-rows
    const int half = w & 1;                  // 0..1: owns 64 keys of each tile

    const short* base = qkv + (size_t)b * T * 3072 + h * 64;

    // Q fragments (B-operand): lane owns q-col q_abs (v11 layout)
    const int q_abs = qbase + pair * 32 + c31;
    const short* qp = base + (size_t)q_abs * 3072 + hi * 8;
    bf16x8 qf[4];
#pragma unroll
    for (int ds = 0; ds < 4; ++ds)
        qf[ds] = *(const bf16x8*)(qp + ds * 16);

    f32x16 acc_o[2];
#pragma unroll
    for (int dt = 0; dt < 2; ++dt)
#pragma unroll
        for (int r = 0; r < 16; ++r) acc_o[dt][r] = 0.f;
    float lacc = 0.f;

    // K staging (waves 4-7): per-thread granule (l&7) of row (l>>3), col XOR'd
    const int w4   = w - 4;
    const int kswz = 8 * ((l & 7) ^ (l >> 3));
    const int sw   = c31 & 7;                // QK read swizzle (v11)

    // V staging (waves 0-3): thread owns keys {2l, 2l+1}, dims w*16..+15 (v11)
    const int k0v = 2 * l;
    const int kk5 = k0v & 31;
    const int pos = (k0v >> 5) * 32 + ((kk5 >> 4) & 1) * 16 + ((kk5 >> 2) & 1) * 8
                  + ((kk5 >> 3) & 1) * 4 + (kk5 & 3);   // even
    const int vg  = pos >> 3;
    const int vpo = pos & 7;
    const int seg = (w & 3) * 16;
    const int dmask = c31 & 15;              // Vt read swizzle source (v11)

    union { uint4 q[2]; unsigned int u[8]; } KA, KB;

    // ---- prologue: stage tile 0 into buffer 0 ----
    if (w >= 4) {
#pragma unroll
        for (int rr = 0; rr < 4; ++rr) {
            const int rowbase = rr * 32 + w4 * 8;
            gload_lds16(base + 1024 + (size_t)(rowbase + (l >> 3)) * 3072 + kswz,
                        &Ks[0][rowbase * 64]);
        }
    } else {
        const short* vp = base + 2048 + (size_t)k0v * 3072 + seg;
        KA.q[0] = *(const uint4*)vp;
        KA.q[1] = *(const uint4*)(vp + 8);
        KB.q[0] = *(const uint4*)(vp + 3072);
        KB.q[1] = *(const uint4*)(vp + 3080);
#pragma unroll
        for (int dd = 0; dd < 16; ++dd) {
            const unsigned int w0 = KA.u[dd >> 1];
            const unsigned int w1 = KB.u[dd >> 1];
            const unsigned int pk = (dd & 1) ? ((w0 >> 16) | (w1 & 0xffff0000u))
                                             : ((w0 & 0xffffu) | (w1 << 16));
            *(unsigned int*)&Vt[0][(seg + dd) * 128 + ((vg ^ dd) << 3) + vpo] = pk;
        }
    }
    __syncthreads();

#pragma unroll 1
    for (int it = 0; it < nkt; ++it) {
        const int j0  = it * 128;
        const int buf = it & 1;
        const int nb  = buf ^ 1;

        // --- issue next-tile prefetch before compute (latency hides) ---
        if (it + 1 < nkt) {
            const int j1 = j0 + 128;
            if (w >= 4) {
#pragma unroll
                for (int rr = 0; rr < 4; ++rr) {
                    const int rowbase = rr * 32 + w4 * 8;
                    gload_lds16(base + 1024 + (size_t)(j1 + rowbase + (l >> 3)) * 3072 + kswz,
                                &Ks[nb][rowbase * 64]);
                }
            } else {
                const short* vp = base + 2048 + (size_t)(j1 + k0v) * 3072 + seg;
                KA.q[0] = *(const uint4*)vp;
                KA.q[1] = *(const uint4*)(vp + 8);
                KB.q[0] = *(const uint4*)(vp + 3072);
                KB.q[1] = *(const uint4*)(vp + 3080);
            }
        }

        // --- S^T = K Q^T on this wave's key-half: s4[kb], keys (2*half+kb)*32.. ---
        f32x16 s4[2];
        __builtin_amdgcn_s_setprio(1);
#pragma unroll
        for (int kb = 0; kb < 2; ++kb) {
            const int kbase = half * 2 + kb;
            const short* krp = &Ks[buf][(kbase * 32 + c31) * 64];
            f32x16 a;
#pragma unroll
            for (int r = 0; r < 16; ++r) a[r] = 0.f;
#pragma unroll
            for (int ds = 0; ds < 4; ++ds) {
                const bf16x8 kf = *(const bf16x8*)&krp[((ds * 2 + hi) ^ sw) << 3];
                a = __builtin_amdgcn_mfma_f32_32x32x16_bf16(kf, qf[ds], a, 0, 0, 0);
            }
            s4[kb] = a;
        }
        __builtin_amdgcn_s_setprio(0);

        // --- causal mask (last tile only; v11 C-layout key formula) ---
        if (it == nkt - 1) {
#pragma unroll
            for (int kb = 0; kb < 2; ++kb)
#pragma unroll
                for (int r = 0; r < 16; ++r) {
                    const int key = j0 + (half * 2 + kb) * 32 + (r & 3) + 8 * (r >> 2) + 4 * hi;
                    if (key > q_abs) s4[kb][r] = -1e30f;
                }
        }

        // --- static-max softmax: P = exp2(S*SC - M0); no cross-lane ops ---
#pragma unroll
        for (int kb = 0; kb < 2; ++kb)
#pragma unroll
            for (int r = 0; r < 16; ++r)
                s4[kb][r] = EXP2(fmaf(s4[kb][r], SC, -M0));

#pragma unroll
        for (int kb = 0; kb < 2; ++kb) {
            float a0 = (s4[kb][0] + s4[kb][1]) + (s4[kb][2] + s4[kb][3]);
            float a1 = (s4[kb][4] + s4[kb][5]) + (s4[kb][6] + s4[kb][7]);
            float a2 = (s4[kb][8] + s4[kb][9]) + (s4[kb][10] + s4[kb][11]);
            float a3 = (s4[kb][12] + s4[kb][13]) + (s4[kb][14] + s4[kb][15]);
            lacc += (a0 + a1) + (a2 + a3);
        }

        // --- O^T += V^T P^T on this key-half: pf straight from regs ---
        __builtin_amdgcn_s_setprio(1);
#pragma unroll
        for (int kb = 0; kb < 2; ++kb) {
#pragma unroll
            for (int hh = 0; hh < 2; ++hh) {
                union { unsigned int u[4]; bf16x8 v; } up;
#pragma unroll
                for (int p = 0; p < 4; ++p)
                    up.u[p] = (unsigned int)(unsigned short)f2bf(s4[kb][hh * 8 + 2 * p])
                            | ((unsigned int)(unsigned short)f2bf(s4[kb][hh * 8 + 2 * p + 1]) << 16);
                const int g = (half * 2 + kb) * 4 + hh * 2 + hi;
#pragma unroll
                for (int dt = 0; dt < 2; ++dt) {
                    const bf16x8 vf = *(const bf16x8*)
                        &Vt[buf][(dt * 32 + c31) * 128 + ((g ^ dmask) << 3)];
                    acc_o[dt] = __builtin_amdgcn_mfma_f32_32x32x16_bf16(vf, up.v, acc_o[dt], 0, 0, 0);
                }
            }
        }
        __builtin_amdgcn_s_setprio(0);

        // --- write prefetched V into spare buffer (after its readers) ---
        if (it + 1 < nkt && w < 4) {
#pragma unroll
            for (int dd = 0; dd < 16; ++dd) {
                const unsigned int w0 = KA.u[dd >> 1];
                const unsigned int w1 = KB.u[dd >> 1];
                const unsigned int pk = (dd & 1) ? ((w0 >> 16) | (w1 & 0xffff0000u))
                                                 : ((w0 & 0xffffu) | (w1 << 16));
                *(unsigned int*)&Vt[nb][(seg + dd) * 128 + ((vg ^ dd) << 3) + vpo] = pk;
            }
        }

        __syncthreads();   // drains K gloads + V writes, frees old buffers
    }

    // ---- cross-wave key-half combine (additive: static-max softmax) ----
    float* accS = (float*)&Ks[0][0];       // 32 KB scratch (both K buffers)
    float* lS   = (float*)&Vt[0][0];       // 1 KB scratch
    const int sb  = (pair * 64 + l) * 32;
    const int sx  = (l & 7) << 2;          // bank-spread XOR within the 32-f32 row
    if (half == 1) {
#pragma unroll
        for (int dt = 0; dt < 2; ++dt)
#pragma unroll
            for (int r = 0; r < 16; ++r)
                accS[sb + ((dt * 16 + r) ^ sx)] = acc_o[dt][r];
        lS[pair * 64 + l] = lacc;
    }
    __syncthreads();
    if (half == 0) {
#pragma unroll
        for (int dt = 0; dt < 2; ++dt)
#pragma unroll
            for (int r = 0; r < 16; ++r)
                acc_o[dt][r] += accS[sb + ((dt * 16 + r) ^ sx)];
        float lt = lacc + lS[pair * 64 + l];
        const float ls  = lt + __shfl_xor(lt, 32);
        const float inv = 1.f / ls;
        short* op = att + ((size_t)(b * T + q_abs)) * 1024 + h * 64;
#pragma unroll
        for (int dt = 0; dt < 2; ++dt)
#pragma unroll
            for (int rg = 0; rg < 4; ++rg) {
                const int d0 = dt * 32 + 8 * rg + 4 * hi;
                short4 pk;
                pk.x = f2bf(acc_o[dt][rg * 4 + 0] * inv);
                pk.y = f2bf(acc_o[dt][rg * 4 + 1] * inv);
                pk.z = f2bf(acc_o[dt][rg * 4 + 2] * inv);
                pk.w = f2bf(acc_o[dt][rg * 4 + 3] * inv);
                *(short4*)(op + d0) = pk;
            }
    }
}

// ---------------------------------------------------------------------------
extern "C" void kernel_launch(void* const* d_in, const int* in_sizes, int n_in,
                              void* d_out, int out_size, void* d_ws, size_t ws_size,
                              hipStream_t stream)
{
    const float* x      = (const float*)d_in[0];   // [B,T,C]
    const float* w_qkv  = (const float*)d_in[1];   // [C,3C]
    const float* b_qkv  = (const float*)d_in[2];   // [3C]
    const float* w_proj = (const float*)d_in[3];   // [C,C]
    const float* b_proj = (const float*)d_in[4];   // [C]
    float* out = (float*)d_out;                    // [B,T,C] fp32

    short* xb     = (short*)d_ws;                        //  8 MB
    short* wqkvt  = xb     + (size_t)M * C;              //  6 MB  [3072][1024]
    short* wprojt = wqkvt  + (size_t)NQKV * C;           //  2 MB  [1024][1024]
    short* qkvb   = wprojt + (size_t)C * C;              // 24 MB  [4096][3072]
    short* attb   = qkvb   + (size_t)M * NQKV;           //  8 MB  [4096][1024]

    prep_all<<<8192, 256, 0, stream>>>(x, xb, w_qkv, wqkvt, w_proj, wprojt);
    gemm_mfma<<<dim3(NQKV / 128, M / 128), 256, 0, stream>>>(xb, wqkvt, b_qkv, qkvb, NQKV, C);
    attn_mfma<<<512, 512, 0, stream>>>(qkvb, attb);
    gemm_mfma_proj<<<dim3(C / 128, M / 64), 256, 0, stream>>>(attb, wprojt, b_proj, out, C, C);
}